// Round 4
// baseline (123.441 us; speedup 1.0000x reference)
//
#include <hip/hip_runtime.h>

// Depthwise 21x21 Gaussian blur, reflect pad 10, 16x3x512x512 fp32.
// Separable: phi[j] = W[ch][10][j] / sqrt(W[ch][10][10]).
// R3 change vs R2: guard-free window formulation. R2's sliding-window k-loop
// (36 iters x 16 guarded stmts) didn't fully unroll -> runtime cmp/cndmask
// per (k,i) pair (~840 extra VALU instr/thread, measured 1460 instr/wave vs
// ~620 irreducible). Now: load win[] to registers (static idx), then
// acc[i] = sum_j ph[j]*win[i+j] with constant bounds -> pure v_fmac.

constexpr int IMG = 512;
constexpr int KS  = 21;
constexpr int RAD = 10;
constexpr int TX  = 64;
constexpr int TY  = 32;
constexpr int HY  = TY + 2 * RAD;     // 52 halo rows
constexpr int SA_STRIDE = 85;         // 85%32=21, coprime -> uniform 2-way (free)
constexpr int SB_STRIDE = 53;         // 53%32=21, coprime -> uniform 2-way (free)

__global__ __launch_bounds__(256, 5) void gauss2d_sep(const float* __restrict__ x,
                                                      const float* __restrict__ W,
                                                      float* __restrict__ out)
{
    __shared__ float sA[HY * SA_STRIDE];   // [row][col] 17.7 KB
    __shared__ float sB[TX * SB_STRIDE];   // [col][row] transposed, 13.6 KB
    __shared__ float sPhi[KS];

    const int tid = threadIdx.x;
    const int tx  = blockIdx.x * TX;
    const int ty  = blockIdx.y * TY;
    const int bc  = blockIdx.z;            // batch*3 + channel
    const int ch  = bc % 3;

    if (tid < KS) {
        const float* wr = W + ch * (KS * KS) + RAD * KS;
        sPhi[tid] = wr[tid] / sqrtf(wr[RAD]);
    }

    const float* __restrict__ xin = x + (size_t)bc * (IMG * IMG);

    // ---- Stage 52x84 input tile, reflect pad. 252 threads = 84 cols x 3 rgroups.
    if (tid < 252) {
        const int rg = (tid >= 168) ? 2 : (tid >= 84 ? 1 : 0);
        const int c  = tid - rg * 84;
        int gc = tx + c - RAD;                       // col reflect hoisted
        gc = (gc < 0) ? -gc : gc;
        gc = (gc >= IMG) ? 2 * IMG - 2 - gc : gc;
        for (int rr = rg; rr < HY; rr += 3) {
            int gr = ty + rr - RAD;
            gr = (gr < 0) ? -gr : gr;
            gr = (gr >= IMG) ? 2 * IMG - 2 - gr : gr;
            sA[rr * SA_STRIDE + c] = xin[gr * IMG + gc];
        }
    }
    __syncthreads();

    // Taps -> wave-uniform (SGPR) registers.
    float ph[KS];
    #pragma unroll
    for (int j = 0; j < KS; ++j)
        ph[j] = __int_as_float(__builtin_amdgcn_readfirstlane(__float_as_int(sPhi[j])));

    // ---- Horizontal pass: 52 rows x 4 chunks of 16 cols = 208 tasks. ----
    // Window-in-registers: 36 ds_read + 336 fmac, no guards.
    if (tid < HY * 4) {
        const int r  = tid >> 2;
        const int c0 = (tid & 3) << 4;
        const float* arow = &sA[r * SA_STRIDE + c0];
        float win[36];
        #pragma unroll
        for (int k = 0; k < 36; ++k) win[k] = arow[k];
        float acc[16];
        #pragma unroll
        for (int i = 0; i < 16; ++i) {
            float a = ph[0] * win[i];
            #pragma unroll
            for (int j = 1; j < KS; ++j) a += ph[j] * win[i + j];
            acc[i] = a;
        }
        #pragma unroll
        for (int i = 0; i < 16; ++i)
            sB[(c0 + i) * SB_STRIDE + r] = acc[i];           // 2-way max
    }
    __syncthreads();

    // ---- Vertical pass: col = tid&63, rows [(tid>>6)*8, +8). 256 tasks. ----
    {
        const int c  = tid & 63;
        const int r0 = (tid >> 6) << 3;
        const float* bcol = &sB[c * SB_STRIDE + r0];
        float win[28];
        #pragma unroll
        for (int k = 0; k < 28; ++k) win[k] = bcol[k];
        float acc[8];
        #pragma unroll
        for (int i = 0; i < 8; ++i) {
            float a = ph[0] * win[i];
            #pragma unroll
            for (int j = 1; j < KS; ++j) a += ph[j] * win[i + j];
            acc[i] = a;
        }
        float* __restrict__ oimg = out + (size_t)bc * (IMG * IMG)
                                 + (size_t)(ty + r0) * IMG + (tx + c);
        #pragma unroll
        for (int i = 0; i < 8; ++i)
            oimg[i * IMG] = acc[i];                          // fully coalesced
    }
}

extern "C" void kernel_launch(void* const* d_in, const int* in_sizes, int n_in,
                              void* d_out, int out_size, void* d_ws, size_t ws_size,
                              hipStream_t stream) {
    const float* x = (const float*)d_in[0];
    const float* W = (const float*)d_in[1];
    float* out     = (float*)d_out;
    dim3 grid(IMG / TX, IMG / TY, 16 * 3);
    gauss2d_sep<<<grid, 256, 0, stream>>>(x, W, out);
}